// Round 11
// baseline (69.497 us; speedup 1.0000x reference)
//
#include <hip/hip_runtime.h>
#include <hip/hip_bf16.h>

#define NS 0.2f

// Problem sizes (fixed): B=8, S=1024, D=512, H=8, OD=64

typedef _Float16 half8 __attribute__((ext_vector_type(8)));
typedef float f32x4 __attribute__((ext_vector_type(4)));
typedef float f32x16 __attribute__((ext_vector_type(16)));

// ---------------------------------------------------------------------------
// stage0: merged BW-bound pass.
//  blocks 0..255   : Q projection, 32 rows each (4 waves x 8 rows), W in regs
//  blocks 256..511 : K projection
//  blocks 512..2687: V/WV f32 -> f16 convert (8 elems/thread)
// ---------------------------------------------------------------------------
__global__ __launch_bounds__(256) void stage0_kernel(
    const float* __restrict__ Q, const float* __restrict__ K,
    const float* __restrict__ V, const float* __restrict__ WQ,
    const float* __restrict__ WK, const float* __restrict__ WV,
    float* __restrict__ aQ, float* __restrict__ aK,
    _Float16* __restrict__ Vh, _Float16* __restrict__ WVh) {
  int bid = blockIdx.x;
  int t = threadIdx.x;
  if (bid < 512) {
    const float* X;
    const float* W;
    float* aX;
    int rb;
    if (bid < 256) { X = Q; W = WQ; aX = aQ; rb = bid; }
    else           { X = K; W = WK; aX = aK; rb = bid - 256; }
    int w = t >> 6, lane = t & 63;
    float4 wr0[8], wr1[8];
#pragma unroll
    for (int h = 0; h < 8; h++) {
      wr0[h] = *(const float4*)(W + h * 512 + lane * 4);
      wr1[h] = *(const float4*)(W + h * 512 + 256 + lane * 4);
    }
#pragma unroll 2
    for (int r = 0; r < 8; r++) {
      int row = rb * 32 + w * 8 + r;
      const float* x = X + (size_t)row * 512;
      float4 x0 = *(const float4*)(x + lane * 4);
      float4 x1 = *(const float4*)(x + 256 + lane * 4);
      float acc[8];
#pragma unroll
      for (int h = 0; h < 8; h++) {
        float a = x0.x * wr0[h].x + x0.y * wr0[h].y + x0.z * wr0[h].z +
                  x0.w * wr0[h].w + x1.x * wr1[h].x + x1.y * wr1[h].y +
                  x1.z * wr1[h].z + x1.w * wr1[h].w;
#pragma unroll
        for (int off = 32; off > 0; off >>= 1) a += __shfl_xor(a, off);
        acc[h] = a;
      }
      if (lane == 0) {
        float* o = aX + (size_t)row * 8;
        o[0] = acc[0]; o[1] = acc[1]; o[2] = acc[2]; o[3] = acc[3];
        o[4] = acc[4]; o[5] = acc[5]; o[6] = acc[6]; o[7] = acc[7];
      }
    }
  } else {
    const size_t n1 = (size_t)8192 * 512;
    size_t i = ((size_t)(bid - 512) * 256 + t) * 8;
    const float* src;
    _Float16* dst;
    size_t j;
    if (i < n1) { src = V; dst = Vh; j = i; }
    else        { src = WV; dst = WVh; j = i - n1; }
    float4 a = *(const float4*)(src + j);
    float4 b = *(const float4*)(src + j + 4);
    half8 h;
    h[0] = (_Float16)a.x; h[1] = (_Float16)a.y;
    h[2] = (_Float16)a.z; h[3] = (_Float16)a.w;
    h[4] = (_Float16)b.x; h[5] = (_Float16)b.y;
    h[6] = (_Float16)b.z; h[7] = (_Float16)b.w;
    *(half8*)(dst + j) = h;
  }
}

// ---------------------------------------------------------------------------
// gemm_f16: Vp = Vh(8192x512) @ WVh.T(512x512) -> f16 C(8192x512)
// 64x64 tile, BK=64, f16 inputs, reg prefetch of tile k+1.
// COMPUTE: mfma_f32_32x32x16_f16 — one 32x32 quadrant per wave.
// Per wave per K-step: 8 ds_read_b128 + 4 MFMA (was 16 + 16 with 16x16x32).
// LDS layout unchanged: slot s of row r holds global k-chunk (s ^ (r&7)).
// A-frag: row = lane&31, k-half = lane>>5 (8 contiguous f16) — analog of the
// verified 16x16 mapping. C/D (m74/m101-verified, dtype-indep):
//   col = lane&31, row = (reg&3) + 8*(reg>>2) + 4*(lane>>5).
// ---------------------------------------------------------------------------
__global__ __launch_bounds__(256) void gemm_f16(
    const _Float16* __restrict__ A, const _Float16* __restrict__ B,
    _Float16* __restrict__ C) {
  __shared__ __align__(16) _Float16 As[64 * 64];
  __shared__ __align__(16) _Float16 Bs[64 * 64];
  int t = threadIdx.x;
  int m0 = blockIdx.x * 64, n0 = blockIdx.y * 64;
  int lane = t & 63, wid = t >> 6;
  int wr = wid >> 1, wc = wid & 1;
  int sr = t >> 2, sq = t & 3;
  int swz = sr & 7;
  const _Float16* ap = A + (size_t)(m0 + sr) * 512;
  const _Float16* bp = B + (size_t)(n0 + sr) * 512;
  int g0 = (2 * sq) ^ swz;
  int g1 = (2 * sq + 1) ^ swz;
  _Float16* awr = As + sr * 64 + 2 * sq * 8;
  _Float16* bwr = Bs + sr * 64 + 2 * sq * 8;
  int fr32 = lane & 31;   // A-row / B-col within the 32x32 quadrant
  int kh = lane >> 5;     // k-half: selects 8 of the 16 K per MFMA
  int Rrow = wr * 32 + fr32;
  int Ccol = wc * 32 + fr32;
  int rswz = Rrow & 7, cswz = Ccol & 7;
  f32x16 acc;
#pragma unroll
  for (int r = 0; r < 16; r++) acc[r] = 0.f;

  uint4 va0 = *(const uint4*)(ap + g0 * 8);
  uint4 va1 = *(const uint4*)(ap + g1 * 8);
  uint4 vb0 = *(const uint4*)(bp + g0 * 8);
  uint4 vb1 = *(const uint4*)(bp + g1 * 8);
  for (int k0 = 0; k0 < 512; k0 += 64) {
    __syncthreads();
    *(uint4*)awr = va0;
    *(uint4*)(awr + 8) = va1;
    *(uint4*)bwr = vb0;
    *(uint4*)(bwr + 8) = vb1;
    if (k0 + 64 < 512) {
      va0 = *(const uint4*)(ap + k0 + 64 + g0 * 8);
      va1 = *(const uint4*)(ap + k0 + 64 + g1 * 8);
      vb0 = *(const uint4*)(bp + k0 + 64 + g0 * 8);
      vb1 = *(const uint4*)(bp + k0 + 64 + g1 * 8);
    }
    __syncthreads();
    half8 af[4], bf[4];
#pragma unroll
    for (int s = 0; s < 4; s++) {
      int g = s * 2 + kh;  // k-chunk (8 f16) within the 64-wide step
      af[s] = *(half8*)(As + Rrow * 64 + ((g ^ rswz) * 8));
      bf[s] = *(half8*)(Bs + Ccol * 64 + ((g ^ cswz) * 8));
    }
#pragma unroll
    for (int s = 0; s < 4; s++)
      acc = __builtin_amdgcn_mfma_f32_32x32x16_f16(af[s], bf[s], acc, 0, 0, 0);
  }
  // C/D layout (m74/m101): col = lane&31, row = (reg&3)+8*(reg>>2)+4*(lane>>5)
  int col = n0 + Ccol;
#pragma unroll
  for (int r = 0; r < 16; r++) {
    int row = m0 + wr * 32 + (r & 3) + 8 * (r >> 2) + 4 * kh;
    C[(size_t)row * 512 + col] = (_Float16)acc[r];
  }
}

// ---------------------------------------------------------------------------
// sortbin (lite): per (b,h) sort + exps + query binning.
// ---------------------------------------------------------------------------
__global__ __launch_bounds__(1024) void sortbin_kernel(
    const float* __restrict__ aK, const float* __restrict__ aQ,
    float* __restrict__ E1g, float* __restrict__ E2g, int* __restrict__ IDXg,
    float* __restrict__ amaxArr, int* __restrict__ binStart,
    int* __restrict__ binData, float* __restrict__ binX) {
  int bh = blockIdx.x, b = bh >> 3, h = bh & 7;
  __shared__ float key[1024];
  __shared__ int idx[1024];
  __shared__ int cnt[32], bstart[33];
  int t = threadIdx.x;
  float k = aK[(size_t)(b * 1024 + t) * 8 + h];
  int id = t;
  for (int len = 2; len <= 1024; len <<= 1) {
    bool up = ((t & len) == 0);
    for (int stride = len >> 1; stride >= 64; stride >>= 1) {
      key[t] = k; idx[t] = id;
      __syncthreads();
      int p = t ^ stride;
      float k2 = key[p];
      int i2 = idx[p];
      __syncthreads();
      bool takeMin = (((t & stride) == 0) == up);
      bool take2 = takeMin ? (k2 < k) : (k2 > k);
      if (take2) { k = k2; id = i2; }
    }
    int s0 = (len >> 1) < 32 ? (len >> 1) : 32;
    for (int stride = s0; stride >= 1; stride >>= 1) {
      float k2 = __shfl_xor(k, stride);
      int i2 = __shfl_xor(id, stride);
      bool takeMin = (((t & stride) == 0) == up);
      bool take2 = takeMin ? (k2 < k) : (k2 > k);
      if (take2) { k = k2; id = i2; }
    }
  }
  key[t] = k; idx[t] = id;
  __syncthreads();
  float amax = key[1023];
  E1g[bh * 1024 + t] = __expf(k - amax);
  E2g[bh * 1024 + t] = __expf(NS * (k - amax));
  IDXg[bh * 1024 + t] = id;
  if (t == 0) amaxArr[bh] = amax;
  float x = aQ[(size_t)(b * 1024 + t) * 8 + h];
  float negx = -x;
  int lo = 0, hi = 1024;
  while (lo < hi) {
    int mid = (lo + hi) >> 1;
    if (key[mid] <= negx) lo = mid + 1; else hi = mid;
  }
  int ix = lo;
  int c = ix >> 5; if (c > 31) c = 31;
  if (t < 32) cnt[t] = 0;
  __syncthreads();
  int slot = atomicAdd(&cnt[c], 1);
  __syncthreads();
  if (t == 0) {
    int s = 0;
    for (int i = 0; i < 32; i++) { bstart[i] = s; s += cnt[i]; }
    bstart[32] = s;
  }
  __syncthreads();
  if (t < 33) binStart[bh * 33 + t] = bstart[t];
  int pos = bstart[c] + slot;
  binData[bh * 1024 + pos] = (t << 11) | ix;
  binX[bh * 1024 + pos] = x;
}

// ---------------------------------------------------------------------------
// ctot: per-chunk totals at full-chip occupancy.
// grid 512 = bh*8+g, block 256 = 4 chunks x 64 d.
// ---------------------------------------------------------------------------
__global__ __launch_bounds__(256) void ctot_kernel(
    const float* __restrict__ E1g, const float* __restrict__ E2g,
    const int* __restrict__ IDXg, const _Float16* __restrict__ Vp,
    float* __restrict__ ct1, float* __restrict__ ct2,
    float* __restrict__ sct1, float* __restrict__ sct2) {
  int blk = blockIdx.x;
  int bh = blk >> 3, g = blk & 7;
  int b = bh >> 3, h = bh & 7;
  __shared__ float E1[128], E2[128];
  __shared__ int IDX[128];
  int t = threadIdx.x;
  if (t < 128) {
    int gi = bh * 1024 + g * 128 + t;
    E1[t] = E1g[gi];
    E2[t] = E2g[gi];
    IDX[t] = IDXg[gi];
  }
  __syncthreads();
  int c = t >> 6, d = t & 63;
  const _Float16* vb = Vp + (size_t)b * 1024 * 512 + h * 64 + d;
  float t1 = 0.f, t2 = 0.f, s1 = 0.f, s2 = 0.f;
#pragma unroll 8
  for (int j = 0; j < 32; j++) {
    int il = c * 32 + j;
    float v = (float)vb[(size_t)IDX[il] * 512];
    float e1 = E1[il], e2 = E2[il];
    t1 += e1 * v; t2 += e2 * v;
    s1 += e1; s2 += e2;
  }
  int cc = g * 4 + c;
  ct1[(bh * 32 + cc) * 64 + d] = t1;
  ct2[(bh * 32 + cc) * 64 + d] = t2;
  if (d == 0) { sct1[bh * 32 + cc] = s1; sct2[bh * 32 + cc] = s2; }
}

// ---------------------------------------------------------------------------
// final: grid 2048 = bh*32 + chunk. Parallel cross-chunk scan prologue,
// P1/P2 prefix tables, 2 LDS reads per query.
// ---------------------------------------------------------------------------
__global__ __launch_bounds__(256) void final_binned(
    const float* __restrict__ E1g, const float* __restrict__ E2g,
    const int* __restrict__ IDXg, const _Float16* __restrict__ Vp,
    const float* __restrict__ ct1, const float* __restrict__ ct2,
    const float* __restrict__ sct1, const float* __restrict__ sct2,
    const float* __restrict__ amaxArr, const int* __restrict__ binStart,
    const int* __restrict__ binData, const float* __restrict__ binX,
    const float* __restrict__ bias, float* __restrict__ out) {
  int blk = blockIdx.x;
  int bh = blk >> 5, c = blk & 31;
  int b = bh >> 3, h = bh & 7;
  int t = threadIdx.x, w = t >> 6, lane = t & 63;
  __shared__ float P1[33][64], P2[33][64];
  __shared__ float G1s[4][64], G2s[4][64];
  __shared__ float scan1[4][64], scan2[4][64];
  __shared__ float sp1[4], sp2[4];
  __shared__ float sS1[33], sS2[33];
  __shared__ float e1c[32], e2c[32];
  int n0 = binStart[bh * 33 + c];
  int n = binStart[bh * 33 + c + 1] - n0;
  if (n == 0) return;
  if (t < 32) {
    e1c[t] = E1g[bh * 1024 + c * 32 + t];
    e2c[t] = E2g[bh * 1024 + c * 32 + t];
  }
  {
    float p1 = 0.f, p2 = 0.f;
#pragma unroll
    for (int kk = 0; kk < 8; kk++) {
      int k = w * 8 + kk;
      float v1 = ct1[(bh * 32 + k) * 64 + lane];
      float v2 = ct2[(bh * 32 + k) * 64 + lane];
      if (k > c) p1 += v1;
      if (k < c) p2 += v2;
    }
    scan1[w][lane] = p1;
    scan2[w][lane] = p2;
    if (lane == 0) {
      float s1 = 0.f, s2 = 0.f;
#pragma unroll
      for (int kk = 0; kk < 8; kk++) {
        int k = w * 8 + kk;
        if (k > c) s1 += sct1[bh * 32 + k];
        if (k < c) s2 += sct2[bh * 32 + k];
      }
      sp1[w] = s1;
      sp2[w] = s2;
    }
  }
  __syncthreads();
  float o1 = scan1[0][lane] + scan1[1][lane] + scan1[2][lane] + scan1[3][lane];
  float o2 = scan2[0][lane] + scan2[1][lane] + scan2[2][lane] + scan2[3][lane];
  float so1 = sp1[0] + sp1[1] + sp1[2] + sp1[3];
  float so2 = sp2[0] + sp2[1] + sp2[2] + sp2[3];
  float f1[8], f2[8];
  {
    const _Float16* vb = Vp + (size_t)b * 1024 * 512 + h * 64 + lane;
    const int* ib = IDXg + bh * 1024 + c * 32 + w * 8;
#pragma unroll
    for (int k2 = 0; k2 < 8; k2++) {
      float v = (float)vb[(size_t)ib[k2] * 512];
      f1[k2] = e1c[w * 8 + k2] * v;
      f2[k2] = e2c[w * 8 + k2] * v;
    }
  }
  float G1 = 0.f, G2 = 0.f;
#pragma unroll
  for (int k2 = 0; k2 < 8; k2++) { G1 += f1[k2]; G2 += f2[k2]; }
  G1s[w][lane] = G1;
  G2s[w][lane] = G2;
  if (t == 0) {
    float s = 0.f;
    sS1[32] = 0.f;
    for (int l = 31; l >= 0; l--) { s += e1c[l]; sS1[l] = s; }
    s = 0.f;
    sS2[0] = 0.f;
    for (int l = 1; l <= 32; l++) { s += e2c[l - 1]; sS2[l] = s; }
  }
  __syncthreads();
  float off1 = 0.f, off2 = 0.f;
#pragma unroll
  for (int w2 = 0; w2 < 4; w2++) {
    float g1 = G1s[w2][lane], g2 = G2s[w2][lane];
    if (w2 > w) off1 += g1;
    if (w2 < w) off2 += g2;
  }
  {
    float p1v[8];
    float s = 0.f;
#pragma unroll
    for (int k2 = 7; k2 >= 0; k2--) { s += f1[k2]; p1v[k2] = s; }
#pragma unroll
    for (int k2 = 0; k2 < 8; k2++) P1[w * 8 + k2][lane] = off1 + p1v[k2];
    float p = 0.f;
#pragma unroll
    for (int k2 = 0; k2 < 8; k2++) { P2[w * 8 + k2][lane] = off2 + p; p += f2[k2]; }
    if (w == 3) P2[32][lane] = off2 + p;
    if (w == 0) P1[32][lane] = 0.f;
  }
  float amax = amaxArr[bh];
  float bi = bias[h * 64 + lane];
  __syncthreads();
  for (int qi = w; qi < n; qi += 4) {
    int rec = binData[bh * 1024 + n0 + qi];
    float x = binX[bh * 1024 + n0 + qi];
    int q = rec >> 11;
    int l = (rec & 2047) - c * 32;  // in [0,32]
    float num1 = o1 + P1[l][lane];
    float num2 = o2 + P2[l][lane];
    float xs = x + amax;
    float ex = __expf(xs), e2x = __expf(NS * xs);
    float Z = ex * (so1 + sS1[l]) + e2x * (so2 + sS2[l]);
    out[((size_t)(b * 1024 + q)) * 512 + h * 64 + lane] =
        (ex * num1 + e2x * num2) / Z + bi;
  }
}

// ---------------------------------------------------------------------------
// Fallback path kernels (small ws): proj + f32 GEMM + direct attention
// ---------------------------------------------------------------------------
__global__ __launch_bounds__(256) void vproj_gemm(
    const float* __restrict__ A, const float* __restrict__ Wv,
    float* __restrict__ C) {
  __shared__ __align__(16) float As[16][68];
  __shared__ __align__(16) float Bs[16][68];
  int t = threadIdx.x;
  int m0 = blockIdx.x * 64, n0 = blockIdx.y * 64;
  int tx = t & 15, ty = t >> 4;
  int lr = t >> 2, lk = (t & 3) * 4;
  float acc[4][4] = {{0.f}};
  const float* ap = A + (size_t)(m0 + lr) * 512 + lk;
  const float* bp = Wv + (size_t)(n0 + lr) * 512 + lk;
  for (int k0 = 0; k0 < 512; k0 += 16) {
    float4 av = *(const float4*)(ap + k0);
    float4 bv = *(const float4*)(bp + k0);
    __syncthreads();
    As[lk + 0][lr] = av.x; As[lk + 1][lr] = av.y;
    As[lk + 2][lr] = av.z; As[lk + 3][lr] = av.w;
    Bs[lk + 0][lr] = bv.x; Bs[lk + 1][lr] = bv.y;
    Bs[lk + 2][lr] = bv.z; Bs[lk + 3][lr] = bv.w;
    __syncthreads();
#pragma unroll
    for (int kk = 0; kk < 16; kk++) {
      float4 a4 = *(const float4*)&As[kk][ty * 4];
      float4 b4 = *(const float4*)&Bs[kk][tx * 4];
      float aa[4] = {a4.x, a4.y, a4.z, a4.w};
      float bb[4] = {b4.x, b4.y, b4.z, b4.w};
#pragma unroll
      for (int i = 0; i < 4; i++)
#pragma unroll
        for (int j = 0; j < 4; j++) acc[i][j] += aa[i] * bb[j];
    }
  }
#pragma unroll
  for (int i = 0; i < 4; i++) {
    float4 o = {acc[i][0], acc[i][1], acc[i][2], acc[i][3]};
    *(float4*)(C + (size_t)(m0 + ty * 4 + i) * 512 + n0 + tx * 4) = o;
  }
}

__global__ __launch_bounds__(256) void direct_kernel(
    const float* __restrict__ aQ, const float* __restrict__ aK,
    const float* __restrict__ Vp, const float* __restrict__ bias,
    float* __restrict__ out) {
  int id = blockIdx.x;
  int qt = id & 15, h = (id >> 4) & 7, b = id >> 7;
  __shared__ float AK[1024], E1s[1024], E2s[1024];
  __shared__ __align__(16) float VT[128][64];
  __shared__ float XQ[64];
  int t = threadIdx.x;
  for (int i = t; i < 1024; i += 256) {
    float a = aK[(size_t)(b * 1024 + i) * 8 + h];
    AK[i] = a; E1s[i] = __expf(a); E2s[i] = __expf(NS * a);
  }
  if (t < 64) XQ[t] = aQ[(size_t)(b * 1024 + qt * 64 + t) * 8 + h];
  __syncthreads();
  int w = t >> 6, d = t & 63;
  float xq[16], ex[16], e2x[16], acc[16], z[16];
#pragma unroll
  for (int qi = 0; qi < 16; qi++) {
    float x = XQ[w * 16 + qi];
    xq[qi] = x; ex[qi] = __expf(x); e2x[qi] = __expf(NS * x);
    acc[qi] = 0.f; z[qi] = 0.f;
  }
  for (int kt = 0; kt < 8; kt++) {
    __syncthreads();
    for (int i = t; i < 128 * 64; i += 256) {
      VT[i >> 6][i & 63] =
          Vp[(size_t)(b * 1024 + kt * 128 + (i >> 6)) * 512 + h * 64 + (i & 63)];
    }
    __syncthreads();
    for (int kk = 0; kk < 128; kk++) {
      int k = kt * 128 + kk;
      float a = AK[k], e1 = E1s[k], e2 = E2s[k];
      float v = VT[kk][d];
#pragma unroll
      for (int qi = 0; qi < 16; qi++) {
        float wsel = (a + xq[qi] > 0.f) ? (ex[qi] * e1) : (e2x[qi] * e2);
        acc[qi] += wsel * v;
        z[qi] += wsel;
      }
    }
  }
#pragma unroll
  for (int qi = 0; qi < 16; qi++) {
    int q = qt * 64 + w * 16 + qi;
    out[(size_t)(b * 1024 + q) * 512 + h * 64 + d] =
        acc[qi] / z[qi] + bias[h * 64 + d];
  }
}

__global__ __launch_bounds__(256) void projQK_fb_kernel(
    const float* __restrict__ Q, const float* __restrict__ K,
    const float* __restrict__ WQ, const float* __restrict__ WK,
    float* __restrict__ aQ, float* __restrict__ aK) {
  int bid = blockIdx.x;
  const float* X;
  const float* W;
  float* aX;
  int rb;
  if (bid < 256) { X = Q; W = WQ; aX = aQ; rb = bid; }
  else           { X = K; W = WK; aX = aK; rb = bid - 256; }
  int t = threadIdx.x;
  int w = t >> 6, lane = t & 63;
  float4 wr0[8], wr1[8];
#pragma unroll
  for (int h = 0; h < 8; h++) {
    wr0[h] = *(const float4*)(W + h * 512 + lane * 4);
    wr1[h] = *(const float4*)(W + h * 512 + 256 + lane * 4);
  }
#pragma unroll 2
  for (int r = 0; r < 8; r++) {
    int row = rb * 32 + w * 8 + r;
    const float* x = X + (size_t)row * 512;
    float4 x0 = *(const float4*)(x + lane * 4);
    float4 x1 = *(const float4*)(x + 256 + lane * 4);
    float acc[8];
#pragma unroll
    for (int h = 0; h < 8; h++) {
      float a = x0.x * wr0[h].x + x0.y * wr0[h].y + x0.z * wr0[h].z +
                x0.w * wr0[h].w + x1.x * wr1[h].x + x1.y * wr1[h].y +
                x1.z * wr1[h].z + x1.w * wr1[h].w;
#pragma unroll
      for (int off = 32; off > 0; off >>= 1) a += __shfl_xor(a, off);
      acc[h] = a;
    }
    if (lane == 0) {
      float* o = aX + (size_t)row * 8;
      o[0] = acc[0]; o[1] = acc[1]; o[2] = acc[2]; o[3] = acc[3];
      o[4] = acc[4]; o[5] = acc[5]; o[6] = acc[6]; o[7] = acc[7];
    }
  }
}

// ---------------------------------------------------------------------------
extern "C" void kernel_launch(void* const* d_in, const int* in_sizes, int n_in,
                              void* d_out, int out_size, void* d_ws,
                              size_t ws_size, hipStream_t stream) {
  const float* Q = (const float*)d_in[0];
  const float* K = (const float*)d_in[1];
  const float* V = (const float*)d_in[2];
  const float* WQ = (const float*)d_in[3];
  const float* WK = (const float*)d_in[4];
  const float* WV = (const float*)d_in[5];
  const float* bias = (const float*)d_in[6];
  float* out = (float*)d_out;
  char* ws = (char*)d_ws;

  // byte offsets (16B aligned)
  const size_t oAQ   = 0;                   // f32 [8192][8]      256 KB
  const size_t oAK   = 262144;              // f32 [8192][8]      256 KB
  const size_t oE1   = 524288;              // f32 [64][1024]     256 KB
  const size_t oE2   = 786432;              // f32 [64][1024]     256 KB
  const size_t oIDX  = 1048576;             // i32 [64][1024]     256 KB
  const size_t oCT1  = 1310720;             // f32 [64][32][64]   512 KB
  const size_t oCT2  = 1835008;             // f32 [64][32][64]   512 KB
  const size_t oSC1  = 2359296;             // f32 [64][32]  (pad 16K)
  const size_t oSC2  = 2375680;
  const size_t oAMX  = 2392064;             // f32 [64]      (pad 4K)
  const size_t oBST  = 2396160;             // i32 [64][33]  (pad 16K)
  const size_t oBDA  = 2412544;             // i32 [64][1024]     256 KB
  const size_t oBX   = 2674688;             // f32 [64][1024]     256 KB
  const size_t oVP   = 2936832;             // f16 [8192][512]    8 MB
  const size_t oVH   = oVP + 8388608;       // f16 [8192][512]    8 MB
  const size_t oWVH  = oVH + 8388608;       // f16 [512][512]     512 KB
  const size_t NEED_MAIN = oWVH + 524288;   // ~20.2 MB
  const size_t NEED_FB = 524288 + 16777216; // ~17 MB

  if (ws_size >= NEED_MAIN) {
    float* aQ = (float*)(ws + oAQ);
    float* aK = (float*)(ws + oAK);
    float* E1g = (float*)(ws + oE1);
    float* E2g = (float*)(ws + oE2);
    int* IDXg = (int*)(ws + oIDX);
    float* ct1 = (float*)(ws + oCT1);
    float* ct2 = (float*)(ws + oCT2);
    float* sct1 = (float*)(ws + oSC1);
    float* sct2 = (float*)(ws + oSC2);
    float* amaxA = (float*)(ws + oAMX);
    int* binSt = (int*)(ws + oBST);
    int* binDa = (int*)(ws + oBDA);
    float* binX = (float*)(ws + oBX);
    _Float16* Vp = (_Float16*)(ws + oVP);
    _Float16* Vh = (_Float16*)(ws + oVH);
    _Float16* WVh = (_Float16*)(ws + oWVH);
    hipLaunchKernelGGL(stage0_kernel, dim3(2688), dim3(256), 0, stream, Q, K,
                       V, WQ, WK, WV, aQ, aK, Vh, WVh);
    hipLaunchKernelGGL(gemm_f16, dim3(128, 8), dim3(256), 0, stream, Vh, WVh,
                       Vp);
    hipLaunchKernelGGL(sortbin_kernel, dim3(64), dim3(1024), 0, stream, aK,
                       aQ, E1g, E2g, IDXg, amaxA, binSt, binDa, binX);
    hipLaunchKernelGGL(ctot_kernel, dim3(512), dim3(256), 0, stream, E1g, E2g,
                       IDXg, Vp, ct1, ct2, sct1, sct2);
    hipLaunchKernelGGL(final_binned, dim3(2048), dim3(256), 0, stream, E1g,
                       E2g, IDXg, Vp, ct1, ct2, sct1, sct2, amaxA, binSt,
                       binDa, binX, bias, out);
  } else if (ws_size >= NEED_FB) {
    float* aQ = (float*)(ws + 0);
    float* aK = (float*)(ws + 262144);
    float* Vpf = (float*)(ws + 524288);
    hipLaunchKernelGGL(projQK_fb_kernel, dim3(512), dim3(256), 0, stream, Q,
                       K, WQ, WK, aQ, aK);
    hipLaunchKernelGGL(vproj_gemm, dim3(128, 8), dim3(256), 0, stream, V, WV,
                       Vpf);
    hipLaunchKernelGGL(direct_kernel, dim3(1024), dim3(256), 0, stream, aQ, aK,
                       Vpf, bias, out);
  }
}

// Round 12
// 66.540 us; speedup vs baseline: 1.0444x; 1.0444x over previous
//
#include <hip/hip_runtime.h>
#include <hip/hip_bf16.h>

#define NS 0.2f

// Problem sizes (fixed): B=8, S=1024, D=512, H=8, OD=64

typedef _Float16 half8 __attribute__((ext_vector_type(8)));
typedef float f32x4 __attribute__((ext_vector_type(4)));

// ---------------------------------------------------------------------------
// projQK: aX[row*8+h] = sum_d X[row][d]*W[h][d]
// grid 1024: blocks 0..511 -> Q, 512..1023 -> K. 16 rows/block (4 waves x 4),
// W staged in LDS once per 16 rows.  [R9-best configuration]
// ---------------------------------------------------------------------------
__global__ __launch_bounds__(256) void projQK_kernel(
    const float* __restrict__ Q, const float* __restrict__ K,
    const float* __restrict__ WQ, const float* __restrict__ WK,
    float* __restrict__ aQ, float* __restrict__ aK) {
  int bid = blockIdx.x;
  const float* X;
  const float* W;
  float* aX;
  int rb;
  if (bid < 512) { X = Q; W = WQ; aX = aQ; rb = bid; }
  else           { X = K; W = WK; aX = aK; rb = bid - 512; }
  __shared__ __align__(16) float Wl[8 * 512];
  int t = threadIdx.x;
#pragma unroll
  for (int i = 0; i < 16; i++) Wl[i * 256 + t] = W[i * 256 + t];
  __syncthreads();
  int w = t >> 6, lane = t & 63;
#pragma unroll
  for (int r = 0; r < 4; r++) {
    int row = rb * 16 + w * 4 + r;
    const float* x = X + (size_t)row * 512;
    float4 x0 = *(const float4*)(x + lane * 4);
    float4 x1 = *(const float4*)(x + 256 + lane * 4);
    float acc[8];
#pragma unroll
    for (int h = 0; h < 8; h++) {
      const float* wl = Wl + h * 512;
      float4 w0 = *(const float4*)(wl + lane * 4);
      float4 w1 = *(const float4*)(wl + 256 + lane * 4);
      float a = x0.x * w0.x + x0.y * w0.y + x0.z * w0.z + x0.w * w0.w +
                x1.x * w1.x + x1.y * w1.y + x1.z * w1.z + x1.w * w1.w;
#pragma unroll
      for (int off = 32; off > 0; off >>= 1) a += __shfl_xor(a, off);
      acc[h] = a;
    }
    if (lane == 0) {
      float* o = aX + (size_t)row * 8;
      o[0] = acc[0]; o[1] = acc[1]; o[2] = acc[2]; o[3] = acc[3];
      o[4] = acc[4]; o[5] = acc[5]; o[6] = acc[6]; o[7] = acc[7];
    }
  }
}

// ---------------------------------------------------------------------------
// convert: V (8192x512 f32) -> Vh f16, WV (512x512 f32) -> WVh f16.
// Pure BW pass; removes all f32->f16 cvt work from the GEMM loop.
// ---------------------------------------------------------------------------
__global__ __launch_bounds__(256) void convert_kernel(
    const float* __restrict__ V, const float* __restrict__ WV,
    _Float16* __restrict__ Vh, _Float16* __restrict__ WVh) {
  const size_t n1 = (size_t)8192 * 512;
  size_t i = ((size_t)blockIdx.x * 256 + threadIdx.x) * 8;
  const float* src;
  _Float16* dst;
  size_t j;
  if (i < n1) { src = V; dst = Vh; j = i; }
  else        { src = WV; dst = WVh; j = i - n1; }
  float4 a = *(const float4*)(src + j);
  float4 b = *(const float4*)(src + j + 4);
  half8 h;
  h[0] = (_Float16)a.x; h[1] = (_Float16)a.y;
  h[2] = (_Float16)a.z; h[3] = (_Float16)a.w;
  h[4] = (_Float16)b.x; h[5] = (_Float16)b.y;
  h[6] = (_Float16)b.z; h[7] = (_Float16)b.w;
  *(half8*)(dst + j) = h;
}

// ---------------------------------------------------------------------------
// gemm_f16: Vp = Vh(8192x512) @ WVh.T(512x512) -> f16 C(8192x512)
// 64x64 tile, BK=64, f16 inputs (no cvt), reg prefetch of tile k+1.
// mfma_f32_16x16x32_f16 (R9-best). LDS slot s of row r holds global k-chunk
// (s ^ (r&7)); reads apply the same XOR involution (rule #21).
// ---------------------------------------------------------------------------
__global__ __launch_bounds__(256) void gemm_f16(
    const _Float16* __restrict__ A, const _Float16* __restrict__ B,
    _Float16* __restrict__ C) {
  __shared__ __align__(16) _Float16 As[64 * 64];
  __shared__ __align__(16) _Float16 Bs[64 * 64];
  int t = threadIdx.x;
  int m0 = blockIdx.x * 64, n0 = blockIdx.y * 64;
  int lane = t & 63, wid = t >> 6;
  int wr = wid >> 1, wc = wid & 1;
  int sr = t >> 2, sq = t & 3;
  int swz = sr & 7;
  const _Float16* ap = A + (size_t)(m0 + sr) * 512;
  const _Float16* bp = B + (size_t)(n0 + sr) * 512;
  int g0 = (2 * sq) ^ swz;
  int g1 = (2 * sq + 1) ^ swz;
  _Float16* awr = As + sr * 64 + 2 * sq * 8;
  _Float16* bwr = Bs + sr * 64 + 2 * sq * 8;
  int fr = lane & 15, fs = lane >> 4;
  f32x4 acc[2][2];
#pragma unroll
  for (int i = 0; i < 2; i++)
#pragma unroll
    for (int j = 0; j < 2; j++)
#pragma unroll
      for (int r = 0; r < 4; r++) acc[i][j][r] = 0.f;

  uint4 va0 = *(const uint4*)(ap + g0 * 8);
  uint4 va1 = *(const uint4*)(ap + g1 * 8);
  uint4 vb0 = *(const uint4*)(bp + g0 * 8);
  uint4 vb1 = *(const uint4*)(bp + g1 * 8);
  for (int k0 = 0; k0 < 512; k0 += 64) {
    __syncthreads();
    *(uint4*)awr = va0;
    *(uint4*)(awr + 8) = va1;
    *(uint4*)bwr = vb0;
    *(uint4*)(bwr + 8) = vb1;
    if (k0 + 64 < 512) {
      va0 = *(const uint4*)(ap + k0 + 64 + g0 * 8);
      va1 = *(const uint4*)(ap + k0 + 64 + g1 * 8);
      vb0 = *(const uint4*)(bp + k0 + 64 + g0 * 8);
      vb1 = *(const uint4*)(bp + k0 + 64 + g1 * 8);
    }
    __syncthreads();
    half8 af[2][2], bf[2][2];
#pragma unroll
    for (int i = 0; i < 2; i++) {
      int R = wr * 32 + i * 16 + fr;
#pragma unroll
      for (int kk = 0; kk < 2; kk++)
        af[i][kk] = *(half8*)(As + R * 64 + (((fs + 4 * kk) ^ (R & 7)) * 8));
    }
#pragma unroll
    for (int j = 0; j < 2; j++) {
      int Cc = wc * 32 + j * 16 + fr;
#pragma unroll
      for (int kk = 0; kk < 2; kk++)
        bf[j][kk] = *(half8*)(Bs + Cc * 64 + (((fs + 4 * kk) ^ (Cc & 7)) * 8));
    }
#pragma unroll
    for (int i = 0; i < 2; i++)
#pragma unroll
      for (int j = 0; j < 2; j++) {
        acc[i][j] = __builtin_amdgcn_mfma_f32_16x16x32_f16(
            af[i][0], bf[j][0], acc[i][j], 0, 0, 0);
        acc[i][j] = __builtin_amdgcn_mfma_f32_16x16x32_f16(
            af[i][1], bf[j][1], acc[i][j], 0, 0, 0);
      }
  }
  // C/D layout (m89-verified): col = lane&15, row = (lane>>4)*4 + reg
#pragma unroll
  for (int i = 0; i < 2; i++)
#pragma unroll
    for (int j = 0; j < 2; j++) {
      int row = m0 + wr * 32 + i * 16 + fs * 4;
      int col = n0 + wc * 32 + j * 16 + fr;
#pragma unroll
      for (int r = 0; r < 4; r++)
        C[(size_t)(row + r) * 512 + col] = (_Float16)acc[i][j][r];
    }
}

// ---------------------------------------------------------------------------
// sortbin (lite): per (b,h) sort + exps + query binning.
// ---------------------------------------------------------------------------
__global__ __launch_bounds__(1024) void sortbin_kernel(
    const float* __restrict__ aK, const float* __restrict__ aQ,
    float* __restrict__ E1g, float* __restrict__ E2g, int* __restrict__ IDXg,
    float* __restrict__ amaxArr, int* __restrict__ binStart,
    int* __restrict__ binData, float* __restrict__ binX) {
  int bh = blockIdx.x, b = bh >> 3, h = bh & 7;
  __shared__ float key[1024];
  __shared__ int idx[1024];
  __shared__ int cnt[32], bstart[33];
  int t = threadIdx.x;
  float k = aK[(size_t)(b * 1024 + t) * 8 + h];
  int id = t;
  for (int len = 2; len <= 1024; len <<= 1) {
    bool up = ((t & len) == 0);
    for (int stride = len >> 1; stride >= 64; stride >>= 1) {
      key[t] = k; idx[t] = id;
      __syncthreads();
      int p = t ^ stride;
      float k2 = key[p];
      int i2 = idx[p];
      __syncthreads();
      bool takeMin = (((t & stride) == 0) == up);
      bool take2 = takeMin ? (k2 < k) : (k2 > k);
      if (take2) { k = k2; id = i2; }
    }
    int s0 = (len >> 1) < 32 ? (len >> 1) : 32;
    for (int stride = s0; stride >= 1; stride >>= 1) {
      float k2 = __shfl_xor(k, stride);
      int i2 = __shfl_xor(id, stride);
      bool takeMin = (((t & stride) == 0) == up);
      bool take2 = takeMin ? (k2 < k) : (k2 > k);
      if (take2) { k = k2; id = i2; }
    }
  }
  key[t] = k; idx[t] = id;
  __syncthreads();
  float amax = key[1023];
  E1g[bh * 1024 + t] = __expf(k - amax);
  E2g[bh * 1024 + t] = __expf(NS * (k - amax));
  IDXg[bh * 1024 + t] = id;
  if (t == 0) amaxArr[bh] = amax;
  float x = aQ[(size_t)(b * 1024 + t) * 8 + h];
  float negx = -x;
  int lo = 0, hi = 1024;
  while (lo < hi) {
    int mid = (lo + hi) >> 1;
    if (key[mid] <= negx) lo = mid + 1; else hi = mid;
  }
  int ix = lo;
  int c = ix >> 5; if (c > 31) c = 31;
  if (t < 32) cnt[t] = 0;
  __syncthreads();
  int slot = atomicAdd(&cnt[c], 1);
  __syncthreads();
  if (t == 0) {
    int s = 0;
    for (int i = 0; i < 32; i++) { bstart[i] = s; s += cnt[i]; }
    bstart[32] = s;
  }
  __syncthreads();
  if (t < 33) binStart[bh * 33 + t] = bstart[t];
  int pos = bstart[c] + slot;
  binData[bh * 1024 + pos] = (t << 11) | ix;
  binX[bh * 1024 + pos] = x;
}

// ---------------------------------------------------------------------------
// ctot: per-chunk totals at full-chip occupancy.
// grid 512 = bh*8+g, block 256 = 4 chunks x 64 d.
// ---------------------------------------------------------------------------
__global__ __launch_bounds__(256) void ctot_kernel(
    const float* __restrict__ E1g, const float* __restrict__ E2g,
    const int* __restrict__ IDXg, const _Float16* __restrict__ Vp,
    float* __restrict__ ct1, float* __restrict__ ct2,
    float* __restrict__ sct1, float* __restrict__ sct2) {
  int blk = blockIdx.x;
  int bh = blk >> 3, g = blk & 7;
  int b = bh >> 3, h = bh & 7;
  __shared__ float E1[128], E2[128];
  __shared__ int IDX[128];
  int t = threadIdx.x;
  if (t < 128) {
    int gi = bh * 1024 + g * 128 + t;
    E1[t] = E1g[gi];
    E2[t] = E2g[gi];
    IDX[t] = IDXg[gi];
  }
  __syncthreads();
  int c = t >> 6, d = t & 63;
  const _Float16* vb = Vp + (size_t)b * 1024 * 512 + h * 64 + d;
  float t1 = 0.f, t2 = 0.f, s1 = 0.f, s2 = 0.f;
#pragma unroll 8
  for (int j = 0; j < 32; j++) {
    int il = c * 32 + j;
    float v = (float)vb[(size_t)IDX[il] * 512];
    float e1 = E1[il], e2 = E2[il];
    t1 += e1 * v; t2 += e2 * v;
    s1 += e1; s2 += e2;
  }
  int cc = g * 4 + c;
  ct1[(bh * 32 + cc) * 64 + d] = t1;
  ct2[(bh * 32 + cc) * 64 + d] = t2;
  if (d == 0) { sct1[bh * 32 + cc] = s1; sct2[bh * 32 + cc] = s2; }
}

// ---------------------------------------------------------------------------
// final: grid 2048 = bh*32 + chunk. Prologue: wave 0 computes this block's
// cross-chunk offsets from raw ct/sct (32-iter scan, L2-hot); then P1/P2
// prefix tables; each query = 2 LDS reads.  [R9-best configuration]
// ---------------------------------------------------------------------------
__global__ __launch_bounds__(256) void final_binned(
    const float* __restrict__ E1g, const float* __restrict__ E2g,
    const int* __restrict__ IDXg, const _Float16* __restrict__ Vp,
    const float* __restrict__ ct1, const float* __restrict__ ct2,
    const float* __restrict__ sct1, const float* __restrict__ sct2,
    const float* __restrict__ amaxArr, const int* __restrict__ binStart,
    const int* __restrict__ binData, const float* __restrict__ binX,
    const float* __restrict__ bias, float* __restrict__ out) {
  int blk = blockIdx.x;
  int bh = blk >> 5, c = blk & 31;
  int b = bh >> 3, h = bh & 7;
  int t = threadIdx.x, w = t >> 6, lane = t & 63;
  __shared__ float P1[33][64], P2[33][64];
  __shared__ float G1s[4][64], G2s[4][64];
  __shared__ float sS1[33], sS2[33];
  __shared__ float e1c[32], e2c[32];
  __shared__ float cofsL1[64], cofsL2[64];
  __shared__ float soL[2];
  int n0 = binStart[bh * 33 + c];
  int n = binStart[bh * 33 + c + 1] - n0;
  if (n == 0) return;
  if (t < 32) {
    e1c[t] = E1g[bh * 1024 + c * 32 + t];
    e2c[t] = E2g[bh * 1024 + c * 32 + t];
  }
  if (t < 64) {  // wave 0: cross-chunk exclusive scans (suffix e1, prefix e2)
    float o1 = 0.f, o2 = 0.f;
#pragma unroll
    for (int k = 0; k < 32; k++) {
      float v1 = ct1[(bh * 32 + k) * 64 + t];
      float v2 = ct2[(bh * 32 + k) * 64 + t];
      if (k > c) o1 += v1;
      if (k < c) o2 += v2;
    }
    cofsL1[t] = o1; cofsL2[t] = o2;
  } else if (t == 64) {
    float s = 0.f;
    for (int k = c + 1; k < 32; k++) s += sct1[bh * 32 + k];
    soL[0] = s;
  } else if (t == 65) {
    float s = 0.f;
    for (int k = 0; k < c; k++) s += sct2[bh * 32 + k];
    soL[1] = s;
  }
  __syncthreads();
  float f1[8], f2[8];
  {
    const _Float16* vb = Vp + (size_t)b * 1024 * 512 + h * 64 + lane;
    const int* ib = IDXg + bh * 1024 + c * 32 + w * 8;
#pragma unroll
    for (int k2 = 0; k2 < 8; k2++) {
      float v = (float)vb[(size_t)ib[k2] * 512];
      f1[k2] = e1c[w * 8 + k2] * v;
      f2[k2] = e2c[w * 8 + k2] * v;
    }
  }
  float G1 = 0.f, G2 = 0.f;
#pragma unroll
  for (int k2 = 0; k2 < 8; k2++) { G1 += f1[k2]; G2 += f2[k2]; }
  G1s[w][lane] = G1;
  G2s[w][lane] = G2;
  if (t == 0) {
    float s = 0.f;
    sS1[32] = 0.f;
    for (int l = 31; l >= 0; l--) { s += e1c[l]; sS1[l] = s; }
    s = 0.f;
    sS2[0] = 0.f;
    for (int l = 1; l <= 32; l++) { s += e2c[l - 1]; sS2[l] = s; }
  }
  __syncthreads();
  float off1 = 0.f, off2 = 0.f;
#pragma unroll
  for (int w2 = 0; w2 < 4; w2++) {
    float g1 = G1s[w2][lane], g2 = G2s[w2][lane];
    if (w2 > w) off1 += g1;
    if (w2 < w) off2 += g2;
  }
  {
    float p1v[8];
    float s = 0.f;
#pragma unroll
    for (int k2 = 7; k2 >= 0; k2--) { s += f1[k2]; p1v[k2] = s; }
#pragma unroll
    for (int k2 = 0; k2 < 8; k2++) P1[w * 8 + k2][lane] = off1 + p1v[k2];
    float p = 0.f;
#pragma unroll
    for (int k2 = 0; k2 < 8; k2++) { P2[w * 8 + k2][lane] = off2 + p; p += f2[k2]; }
    if (w == 3) P2[32][lane] = off2 + p;
    if (w == 0) P1[32][lane] = 0.f;
  }
  float o1 = cofsL1[lane];
  float o2 = cofsL2[lane];
  float so1 = soL[0];
  float so2 = soL[1];
  float amax = amaxArr[bh];
  float bi = bias[h * 64 + lane];
  __syncthreads();
  for (int qi = w; qi < n; qi += 4) {
    int rec = binData[bh * 1024 + n0 + qi];
    float x = binX[bh * 1024 + n0 + qi];
    int q = rec >> 11;
    int l = (rec & 2047) - c * 32;  // in [0,32]
    float num1 = o1 + P1[l][lane];
    float num2 = o2 + P2[l][lane];
    float xs = x + amax;
    float ex = __expf(xs), e2x = __expf(NS * xs);
    float Z = ex * (so1 + sS1[l]) + e2x * (so2 + sS2[l]);
    out[((size_t)(b * 1024 + q)) * 512 + h * 64 + lane] =
        (ex * num1 + e2x * num2) / Z + bi;
  }
}

// ---------------------------------------------------------------------------
// Fallback path kernels (small ws): proj + f32 GEMM + direct attention
// ---------------------------------------------------------------------------
__global__ __launch_bounds__(256) void vproj_gemm(
    const float* __restrict__ A, const float* __restrict__ Wv,
    float* __restrict__ C) {
  __shared__ __align__(16) float As[16][68];
  __shared__ __align__(16) float Bs[16][68];
  int t = threadIdx.x;
  int m0 = blockIdx.x * 64, n0 = blockIdx.y * 64;
  int tx = t & 15, ty = t >> 4;
  int lr = t >> 2, lk = (t & 3) * 4;
  float acc[4][4] = {{0.f}};
  const float* ap = A + (size_t)(m0 + lr) * 512 + lk;
  const float* bp = Wv + (size_t)(n0 + lr) * 512 + lk;
  for (int k0 = 0; k0 < 512; k0 += 16) {
    float4 av = *(const float4*)(ap + k0);
    float4 bv = *(const float4*)(bp + k0);
    __syncthreads();
    As[lk + 0][lr] = av.x; As[lk + 1][lr] = av.y;
    As[lk + 2][lr] = av.z; As[lk + 3][lr] = av.w;
    Bs[lk + 0][lr] = bv.x; Bs[lk + 1][lr] = bv.y;
    Bs[lk + 2][lr] = bv.z; Bs[lk + 3][lr] = bv.w;
    __syncthreads();
#pragma unroll
    for (int kk = 0; kk < 16; kk++) {
      float4 a4 = *(const float4*)&As[kk][ty * 4];
      float4 b4 = *(const float4*)&Bs[kk][tx * 4];
      float aa[4] = {a4.x, a4.y, a4.z, a4.w};
      float bb[4] = {b4.x, b4.y, b4.z, b4.w};
#pragma unroll
      for (int i = 0; i < 4; i++)
#pragma unroll
        for (int j = 0; j < 4; j++) acc[i][j] += aa[i] * bb[j];
    }
  }
#pragma unroll
  for (int i = 0; i < 4; i++) {
    float4 o = {acc[i][0], acc[i][1], acc[i][2], acc[i][3]};
    *(float4*)(C + (size_t)(m0 + ty * 4 + i) * 512 + n0 + tx * 4) = o;
  }
}

__global__ __launch_bounds__(256) void direct_kernel(
    const float* __restrict__ aQ, const float* __restrict__ aK,
    const float* __restrict__ Vp, const float* __restrict__ bias,
    float* __restrict__ out) {
  int id = blockIdx.x;
  int qt = id & 15, h = (id >> 4) & 7, b = id >> 7;
  __shared__ float AK[1024], E1s[1024], E2s[1024];
  __shared__ __align__(16) float VT[128][64];
  __shared__ float XQ[64];
  int t = threadIdx.x;
  for (int i = t; i < 1024; i += 256) {
    float a = aK[(size_t)(b * 1024 + i) * 8 + h];
    AK[i] = a; E1s[i] = __expf(a); E2s[i] = __expf(NS * a);
  }
  if (t < 64) XQ[t] = aQ[(size_t)(b * 1024 + qt * 64 + t) * 8 + h];
  __syncthreads();
  int w = t >> 6, d = t & 63;
  float xq[16], ex[16], e2x[16], acc[16], z[16];
#pragma unroll
  for (int qi = 0; qi < 16; qi++) {
    float x = XQ[w * 16 + qi];
    xq[qi] = x; ex[qi] = __expf(x); e2x[qi] = __expf(NS * x);
    acc[qi] = 0.f; z[qi] = 0.f;
  }
  for (int kt = 0; kt < 8; kt++) {
    __syncthreads();
    for (int i = t; i < 128 * 64; i += 256) {
      VT[i >> 6][i & 63] =
          Vp[(size_t)(b * 1024 + kt * 128 + (i >> 6)) * 512 + h * 64 + (i & 63)];
    }
    __syncthreads();
    for (int kk = 0; kk < 128; kk++) {
      int k = kt * 128 + kk;
      float a = AK[k], e1 = E1s[k], e2 = E2s[k];
      float v = VT[kk][d];
#pragma unroll
      for (int qi = 0; qi < 16; qi++) {
        float wsel = (a + xq[qi] > 0.f) ? (ex[qi] * e1) : (e2x[qi] * e2);
        acc[qi] += wsel * v;
        z[qi] += wsel;
      }
    }
  }
#pragma unroll
  for (int qi = 0; qi < 16; qi++) {
    int q = qt * 64 + w * 16 + qi;
    out[(size_t)(b * 1024 + q) * 512 + h * 64 + d] =
        acc[qi] / z[qi] + bias[h * 64 + d];
  }
}

__global__ __launch_bounds__(256) void projQK_fb_kernel(
    const float* __restrict__ Q, const float* __restrict__ K,
    const float* __restrict__ WQ, const float* __restrict__ WK,
    float* __restrict__ aQ, float* __restrict__ aK) {
  int bid = blockIdx.x;
  const float* X;
  const float* W;
  float* aX;
  int rb;
  if (bid < 512) { X = Q; W = WQ; aX = aQ; rb = bid; }
  else           { X = K; W = WK; aX = aK; rb = bid - 512; }
  __shared__ __align__(16) float Wl[8 * 512];
  int t = threadIdx.x;
#pragma unroll
  for (int i = 0; i < 16; i++) Wl[i * 256 + t] = W[i * 256 + t];
  __syncthreads();
  int w = t >> 6, lane = t & 63;
#pragma unroll
  for (int r = 0; r < 4; r++) {
    int row = rb * 16 + w * 4 + r;
    const float* x = X + (size_t)row * 512;
    float4 x0 = *(const float4*)(x + lane * 4);
    float4 x1 = *(const float4*)(x + 256 + lane * 4);
    float acc[8];
#pragma unroll
    for (int h = 0; h < 8; h++) {
      const float* wl = Wl + h * 512;
      float4 w0 = *(const float4*)(wl + lane * 4);
      float4 w1 = *(const float4*)(wl + 256 + lane * 4);
      float a = x0.x * w0.x + x0.y * w0.y + x0.z * w0.z + x0.w * w0.w +
                x1.x * w1.x + x1.y * w1.y + x1.z * w1.z + x1.w * w1.w;
#pragma unroll
      for (int off = 32; off > 0; off >>= 1) a += __shfl_xor(a, off);
      acc[h] = a;
    }
    if (lane == 0) {
      float* o = aX + (size_t)row * 8;
      o[0] = acc[0]; o[1] = acc[1]; o[2] = acc[2]; o[3] = acc[3];
      o[4] = acc[4]; o[5] = acc[5]; o[6] = acc[6]; o[7] = acc[7];
    }
  }
}

// ---------------------------------------------------------------------------
extern "C" void kernel_launch(void* const* d_in, const int* in_sizes, int n_in,
                              void* d_out, int out_size, void* d_ws,
                              size_t ws_size, hipStream_t stream) {
  const float* Q = (const float*)d_in[0];
  const float* K = (const float*)d_in[1];
  const float* V = (const float*)d_in[2];
  const float* WQ = (const float*)d_in[3];
  const float* WK = (const float*)d_in[4];
  const float* WV = (const float*)d_in[5];
  const float* bias = (const float*)d_in[6];
  float* out = (float*)d_out;
  char* ws = (char*)d_ws;

  // byte offsets (16B aligned)
  const size_t oAQ   = 0;                   // f32 [8192][8]      256 KB
  const size_t oAK   = 262144;              // f32 [8192][8]      256 KB
  const size_t oE1   = 524288;              // f32 [64][1024]     256 KB
  const size_t oE2   = 786432;              // f32 [64][1024]     256 KB
  const size_t oIDX  = 1048576;             // i32 [64][1024]     256 KB
  const size_t oCT1  = 1310720;             // f32 [64][32][64]   512 KB
  const size_t oCT2  = 1835008;             // f32 [64][32][64]   512 KB
  const size_t oSC1  = 2359296;             // f32 [64][32]  (pad 16K)
  const size_t oSC2  = 2375680;
  const size_t oAMX  = 2392064;             // f32 [64]      (pad 4K)
  const size_t oBST  = 2396160;             // i32 [64][33]  (pad 16K)
  const size_t oBDA  = 2412544;             // i32 [64][1024]     256 KB
  const size_t oBX   = 2674688;             // f32 [64][1024]     256 KB
  const size_t oVP   = 2936832;             // f16 [8192][512]    8 MB
  const size_t oVH   = oVP + 8388608;       // f16 [8192][512]    8 MB
  const size_t oWVH  = oVH + 8388608;       // f16 [512][512]     512 KB
  const size_t NEED_MAIN = oWVH + 524288;   // ~20.2 MB
  const size_t NEED_FB = 524288 + 16777216; // ~17 MB

  if (ws_size >= NEED_MAIN) {
    float* aQ = (float*)(ws + oAQ);
    float* aK = (float*)(ws + oAK);
    float* E1g = (float*)(ws + oE1);
    float* E2g = (float*)(ws + oE2);
    int* IDXg = (int*)(ws + oIDX);
    float* ct1 = (float*)(ws + oCT1);
    float* ct2 = (float*)(ws + oCT2);
    float* sct1 = (float*)(ws + oSC1);
    float* sct2 = (float*)(ws + oSC2);
    float* amaxA = (float*)(ws + oAMX);
    int* binSt = (int*)(ws + oBST);
    int* binDa = (int*)(ws + oBDA);
    float* binX = (float*)(ws + oBX);
    _Float16* Vp = (_Float16*)(ws + oVP);
    _Float16* Vh = (_Float16*)(ws + oVH);
    _Float16* WVh = (_Float16*)(ws + oWVH);
    hipLaunchKernelGGL(projQK_kernel, dim3(1024), dim3(256), 0, stream, Q, K,
                       WQ, WK, aQ, aK);
    hipLaunchKernelGGL(convert_kernel, dim3(2176), dim3(256), 0, stream, V,
                       WV, Vh, WVh);
    hipLaunchKernelGGL(gemm_f16, dim3(128, 8), dim3(256), 0, stream, Vh, WVh,
                       Vp);
    hipLaunchKernelGGL(sortbin_kernel, dim3(64), dim3(1024), 0, stream, aK,
                       aQ, E1g, E2g, IDXg, amaxA, binSt, binDa, binX);
    hipLaunchKernelGGL(ctot_kernel, dim3(512), dim3(256), 0, stream, E1g, E2g,
                       IDXg, Vp, ct1, ct2, sct1, sct2);
    hipLaunchKernelGGL(final_binned, dim3(2048), dim3(256), 0, stream, E1g,
                       E2g, IDXg, Vp, ct1, ct2, sct1, sct2, amaxA, binSt,
                       binDa, binX, bias, out);
  } else if (ws_size >= NEED_FB) {
    float* aQ = (float*)(ws + 0);
    float* aK = (float*)(ws + 262144);
    float* Vpf = (float*)(ws + 524288);
    hipLaunchKernelGGL(projQK_fb_kernel, dim3(1024), dim3(256), 0, stream, Q,
                       K, WQ, WK, aQ, aK);
    hipLaunchKernelGGL(vproj_gemm, dim3(128, 8), dim3(256), 0, stream, V, WV,
                       Vpf);
    hipLaunchKernelGGL(direct_kernel, dim3(1024), dim3(256), 0, stream, aQ, aK,
                       Vpf, bias, out);
  }
}